// Round 5
// baseline (241.875 us; speedup 1.0000x reference)
//
#include <hip/hip_runtime.h>

#define KK 32
#define HH 6
#define OO 31
#define EPS 1e-6f
#define PTS_BLK 256              // 256 pts/block; 4 waves x o-quarter x M=4 pts/lane
#define V_DW (KK * 4 * HH * 8)   // 6144 dwords: V[k][oc(4)][h(6)][8]

typedef float f32x16 __attribute__((ext_vector_type(16)));
typedef float f32x4  __attribute__((ext_vector_type(4)));

// Sigma-folded, o-chunked, zero-padded W. 24.6 KB, rebuilt each launch by the
// prep kernel (inputs may be re-poisoned between iterations).
// Layout: V[k][oc][h][o8], o = oc*8 + o8, col o==31 zero-padded.
//   h=0: W0 - (W3+W5)/s2   h=1: -W1/s2 (x g*dy)   h=2: -W2/s2 (x g*dx)
//   h=3: W3/s4 (x g*dy^2)  h=4: W4/s4 (x g*dx*dy) h=5: W5/s4 (x g*dx^2)
__device__ __align__(256) float V_dev[V_DW];

__global__ void hermite_prep_kernel(const float* __restrict__ W,
                                    const float* __restrict__ sigmas)
{
    int j = blockIdx.x * 256 + threadIdx.x;
    if (j >= V_DW) return;
    int k  = j / 192;
    int r  = j - k * 192;
    int oc = r / 48;
    int r2 = r - oc * 48;
    int h  = r2 >> 3;
    int o  = oc * 8 + (r2 & 7);
    float s  = sigmas[k];
    float s2 = s * s;
    float i2 = 1.0f / (s2 + EPS);
    float i4 = 1.0f / (s2 * s2 + EPS);
    float v = 0.0f;
    if (o < OO) {
        const float* Wk = W + k * (HH * OO);
        float w = Wk[h * OO + o];
        if (h == 0)      v = w - i2 * (Wk[3 * OO + o] + Wk[5 * OO + o]);
        else if (h <= 2) v = -i2 * w;
        else             v = i4 * w;
    }
    V_dev[j] = v;
}

// o-quarter split: wave w owns outputs [8w, 8w+8) for ALL 256 block points,
// M=4 points/lane. Per (wave, k): ONE 48-dword chunk (the wave's o8 x 6h
// slice) via 3x s_load_dwordx16 -> 48 SGPR, feeding 4 pts x 48 = 192 FMAs
// (384 cyc) per lgkmcnt(0). With 4 waves/SIMD: 4*384/(384+L~600) = 1.5 ->
// VALU-saturated despite the unhidden SMEM latency (SMEM returns may be OOO
// so only lgkmcnt(0) is safe; loads+wait in ONE asm so consumers data-depend
// on the asm outputs -- no hoist hazard). The wave's V base is hoisted to
// SGPR via readfirstlane so the "s" asm constraint is satisfiable.
__global__ __launch_bounds__(256, 4) void hermite_fused_kernel(
    const float* __restrict__ mlp,     // [P, OO]
    const float* __restrict__ cd,      // [P, KK, 2]
    const float* __restrict__ gw,      // [P, KK]
    float* __restrict__ out)           // [P, OO]
{
    __shared__ float smem[PTS_BLK * OO];   // 7936 dwords = 31744 B

    const int tid  = threadIdx.x;
    const int lane = tid & 63;
    const int wv   = tid >> 6;                       // o-block (wave-uniform)
    const int p0   = blockIdx.x * PTS_BLK + lane;    // point m -> p0 + 64*m

    // Per-point rows: cd = 64 dw/pt, gw = 32 dw/pt. m-stride: 64 pts.
    const float4* __restrict__ cdv = (const float4*)(cd + (size_t)p0 * (KK * 2));
    const float4* __restrict__ gwv = (const float4*)(gw + (size_t)p0 * KK);
    // float4 strides between m-points: cd 64*64/4 = 1024, gw 64*32/4 = 512.

    float acc[32];                                   // [m][o8]
#pragma unroll
    for (int i = 0; i < 32; ++i) acc[i] = 0.0f;

    // Wave-uniform o-slice base, hoisted to SGPR (readfirstlane) so the
    // s_load address constraint "s" is satisfiable.
    const int wv_s = __builtin_amdgcn_readfirstlane(wv);
    const float* Vw = V_dev + wv_s * 48;

#pragma unroll 1
    for (int kt = 0; kt < 4; ++kt) {                 // 8 k per iteration
        float ga[4][8];                              // gw staged 8k x 4 pts
#pragma unroll
        for (int m = 0; m < 4; ++m) {
#pragma unroll
            for (int i = 0; i < 2; ++i) {
                float4 t = gwv[m * 512 + kt * 2 + i];
                ga[m][4 * i + 0] = t.x; ga[m][4 * i + 1] = t.y;
                ga[m][4 * i + 2] = t.z; ga[m][4 * i + 3] = t.w;
            }
        }
#pragma unroll
        for (int jj = 0; jj < 4; ++jj) {             // 2 k per jj
            float c[4][4];                           // cd staged 2k x 4 pts
#pragma unroll
            for (int m = 0; m < 4; ++m) {
                float4 t = cdv[m * 1024 + kt * 4 + jj];
                c[m][0] = t.x; c[m][1] = t.y; c[m][2] = t.z; c[m][3] = t.w;
            }
#pragma unroll
            for (int j2 = 0; j2 < 2; ++j2) {
                const int k = kt * 8 + jj * 2 + j2;
                const float* pk = Vw + k * 192;
                f32x16 t0, t1, t2;
                asm volatile("s_load_dwordx16 %0, %3, 0x0\n\t"
                             "s_load_dwordx16 %1, %3, 0x40\n\t"
                             "s_load_dwordx16 %2, %3, 0x80\n\t"
                             "s_waitcnt lgkmcnt(0)"
                             : "=&s"(t0), "=&s"(t1), "=&s"(t2)
                             : "s"(pk));
#pragma unroll
                for (int m = 0; m < 4; ++m) {
                    float dx = c[m][2 * j2], dy = c[m][2 * j2 + 1];
                    float g  = ga[m][jj * 2 + j2];
                    float d1 = g * dy, d2 = g * dx;
                    float d3 = d1 * dy, d4 = d1 * dx, d5 = d2 * dx;
#pragma unroll
                    for (int o = 0; o < 8; ++o) {
                        float a = acc[m * 8 + o];
                        a = fmaf(g,  t0[o],     a);
                        a = fmaf(d1, t0[8 + o], a);
                        a = fmaf(d2, t1[o],     a);
                        a = fmaf(d3, t1[8 + o], a);
                        a = fmaf(d4, t2[o],     a);
                        a = fmaf(d5, t2[8 + o], a);
                        acc[m * 8 + o] = a;
                    }
                }
            }
        }
    }

    // Epilogue: transpose through LDS. Thread holds (pt = m*64+lane,
    // o = wv*8+oo). dw-addr = pt*31 + o -> banks (31*lane + c) mod 32:
    // 2 lanes/bank = free. Guard o==31 (padded col of wave 3): writing it
    // would alias the NEXT point's o=0 (addr p*31+31 == (p+1)*31).
#pragma unroll
    for (int m = 0; m < 4; ++m) {
#pragma unroll
        for (int o = 0; o < 8; ++o) {
            if (wv * 8 + o < OO)
                smem[(m * 64 + lane) * OO + wv * 8 + o] = acc[m * 8 + o];
        }
    }
    __syncthreads();

    {
        const size_t blk_dw = (size_t)blockIdx.x * (PTS_BLK * OO);
        const f32x4* __restrict__ mlpv = (const f32x4*)(mlp + blk_dw);
        f32x4* __restrict__ outv = (f32x4*)(out + blk_dw);
        const f32x4* mixv = (const f32x4*)smem;
#pragma unroll 2
        for (int j = tid; j < (PTS_BLK * OO) / 4; j += 256) {
            f32x4 m = __builtin_nontemporal_load(&mlpv[j]);
            f32x4 x = mixv[j];
            f32x4 r = m * x;
            __builtin_nontemporal_store(r, &outv[j]);
        }
    }
}

extern "C" void kernel_launch(void* const* d_in, const int* in_sizes, int n_in,
                              void* d_out, int out_size, void* d_ws, size_t ws_size,
                              hipStream_t stream)
{
    const float* mlp    = (const float*)d_in[0]; // [B,N,O]
    const float* cd     = (const float*)d_in[1]; // [B,N,K,2]
    const float* sigmas = (const float*)d_in[2]; // [K]
    const float* gw     = (const float*)d_in[3]; // [B,N,K]
    const float* W      = (const float*)d_in[4]; // [K,H,O]
    float* out          = (float*)d_out;

    const int P = in_sizes[3] / KK;              // B*N = 262144

    hermite_prep_kernel<<<(V_DW + 255) / 256, 256, 0, stream>>>(W, sigmas);
    hermite_fused_kernel<<<P / PTS_BLK, 256, 0, stream>>>(mlp, cd, gw, out);
}

// Round 6
// 204.833 us; speedup vs baseline: 1.1808x; 1.1808x over previous
//
#include <hip/hip_runtime.h>

#define KK 32
#define HH 6
#define OO 31
#define EPS 1e-6f
#define PTS_BLK 256              // M=1: 256 threads, 1 pt/thread, full o per thread
#define V_DW (KK * 4 * HH * 8)   // 6144 dwords: V[k][oc(4)][h(6)][8]

typedef float f32x16 __attribute__((ext_vector_type(16)));
typedef float f32x4  __attribute__((ext_vector_type(4)));

// Sigma-folded, o-chunked, zero-padded W. 24.6 KB, rebuilt each launch by the
// prep kernel (inputs may be re-poisoned between iterations).
// Layout: V[k][oc][h][o8], o = oc*8 + o8, col o==31 zero-padded.
//   h=0: W0 - (W3+W5)/s2   h=1: -W1/s2 (x g*dy)   h=2: -W2/s2 (x g*dx)
//   h=3: W3/s4 (x g*dy^2)  h=4: W4/s4 (x g*dx*dy) h=5: W5/s4 (x g*dx^2)
__device__ __align__(256) float V_dev[V_DW];

__global__ void hermite_prep_kernel(const float* __restrict__ W,
                                    const float* __restrict__ sigmas)
{
    int j = blockIdx.x * 256 + threadIdx.x;
    if (j >= V_DW) return;
    int k  = j / 192;
    int r  = j - k * 192;
    int oc = r / 48;
    int r2 = r - oc * 48;
    int h  = r2 >> 3;
    int o  = oc * 8 + (r2 & 7);
    float s  = sigmas[k];
    float s2 = s * s;
    float i2 = 1.0f / (s2 + EPS);
    float i4 = 1.0f / (s2 * s2 + EPS);
    float v = 0.0f;
    if (o < OO) {
        const float* Wk = W + k * (HH * OO);
        float w = Wk[h * OO + o];
        if (h == 0)      v = w - i2 * (Wk[3 * OO + o] + Wk[5 * OO + o]);
        else if (h <= 2) v = -i2 * w;
        else             v = i4 * w;
    }
    V_dev[j] = v;
}

// One (k, 8-output) chunk: 48 wave-uniform V dwords -> SGPRs via SMEM (no
// 64-lane replication), then 48 FMAs with the SGPR as the one allowed scalar
// operand. Loads + lgkmcnt(0) in ONE asm: consumers data-depend on the asm
// outputs (no hoist hazard); SMEM returns may be OOO so only lgkmcnt(0) is
// safe (no counted prefetch on the scalar path).
#define CHUNK(PC, OCB)                                                     \
    {                                                                      \
        f32x16 t0, t1, t2;                                                 \
        asm volatile("s_load_dwordx16 %0, %3, 0x0\n\t"                     \
                     "s_load_dwordx16 %1, %3, 0x40\n\t"                    \
                     "s_load_dwordx16 %2, %3, 0x80\n\t"                    \
                     "s_waitcnt lgkmcnt(0)"                                \
                     : "=&s"(t0), "=&s"(t1), "=&s"(t2)                     \
                     : "s"(PC));                                           \
        _Pragma("unroll")                                                  \
        for (int o = 0; o < 8; ++o) {                                      \
            float a = acc[(OCB) + o];                                      \
            a = fmaf(g,  t0[o],     a);                                    \
            a = fmaf(d1, t0[8 + o], a);                                    \
            a = fmaf(d2, t1[o],     a);                                    \
            a = fmaf(d3, t1[8 + o], a);                                    \
            a = fmaf(d4, t2[o],     a);                                    \
            a = fmaf(d5, t2[8 + o], a);                                    \
            acc[(OCB) + o] = a;                                            \
        }                                                                  \
    }

// K$-window alignment: V_dev (24.6 KB) > scalar K$ (16 KB), and 16 desynced
// waves/CU sweeping it cyclically defeat LRU -> every chunk load pays L2
// (~600 cyc incl. queueing) and duty = 4 waves x 96 cyc / (96+600) = 55%
// (the measured R2 VALUBusy). Fix: tile k into 4 x 8k and __syncthreads()
// per tile so the block's 4 waves stay inside one 1.5 KB V window; <=4
// blocks/CU with bounded drift keep the live V set ~<=12 KB < K$ -> chunk
// loads become K$ hits and the 4 resident waves/SIMD saturate VALU.
// cd/gw tile loads issue BEFORE the barrier (the pre-barrier vmcnt(0) drain
// overlaps their latency with the sync slack).
__global__ __launch_bounds__(256, 4) void hermite_fused_kernel(
    const float* __restrict__ mlp,     // [P, OO]
    const float* __restrict__ cd,      // [P, KK, 2]
    const float* __restrict__ gw,      // [P, KK]
    float* __restrict__ out)           // [P, OO]
{
    __shared__ float smem[PTS_BLK * OO];   // 7936 dwords = 31744 B

    const int tid = threadIdx.x;
    const int p   = blockIdx.x * PTS_BLK + tid;
    const float4* __restrict__ cdv = (const float4*)(cd + (size_t)p * (KK * 2));
    const float4* __restrict__ gwv = (const float4*)(gw + (size_t)p * KK);

    float acc[32];
#pragma unroll
    for (int o = 0; o < 32; ++o) acc[o] = 0.0f;

    const float* __restrict__ Vb = V_dev;

#pragma unroll 1
    for (int kt = 0; kt < 4; ++kt) {               // 8 k per tile
        float ga[8];
#pragma unroll
        for (int i = 0; i < 2; ++i) {
            float4 t = gwv[kt * 2 + i];
            ga[4 * i + 0] = t.x; ga[4 * i + 1] = t.y;
            ga[4 * i + 2] = t.z; ga[4 * i + 3] = t.w;
        }
        float c[16];
#pragma unroll
        for (int i = 0; i < 4; ++i) {
            float4 t = cdv[kt * 4 + i];
            c[4 * i + 0] = t.x; c[4 * i + 1] = t.y;
            c[4 * i + 2] = t.z; c[4 * i + 3] = t.w;
        }

        __syncthreads();                           // align waves into V window

#pragma unroll
        for (int j = 0; j < 8; ++j) {
            float dx = c[2 * j], dy = c[2 * j + 1];
            float g  = ga[j];
            float d1 = g * dy, d2 = g * dx;
            float d3 = d1 * dy, d4 = d1 * dx, d5 = d2 * dx;
            const float* pk = Vb + (kt * 8 + j) * 192;
            CHUNK(pk,        0)
            CHUNK(pk + 48,   8)
            CHUNK(pk + 96,  16)
            CHUNK(pk + 144, 24)
        }
    }

    // Epilogue: transpose through LDS for coalesced float4 mlp*mix -> out.
    // Write banks (31*tid + o) mod 32 = (o - tid) mod 32: conflict-free.
#pragma unroll
    for (int o = 0; o < OO; ++o) smem[tid * OO + o] = acc[o];
    __syncthreads();

    {
        const size_t blk_dw = (size_t)blockIdx.x * (PTS_BLK * OO);
        const f32x4* __restrict__ mlpv = (const f32x4*)(mlp + blk_dw);
        f32x4* __restrict__ outv = (f32x4*)(out + blk_dw);
        const f32x4* mixv = (const f32x4*)smem;
#pragma unroll 2
        for (int j = tid; j < (PTS_BLK * OO) / 4; j += 256) {
            f32x4 m = __builtin_nontemporal_load(&mlpv[j]);
            f32x4 x = mixv[j];
            f32x4 r = m * x;
            __builtin_nontemporal_store(r, &outv[j]);
        }
    }
}

extern "C" void kernel_launch(void* const* d_in, const int* in_sizes, int n_in,
                              void* d_out, int out_size, void* d_ws, size_t ws_size,
                              hipStream_t stream)
{
    const float* mlp    = (const float*)d_in[0]; // [B,N,O]
    const float* cd     = (const float*)d_in[1]; // [B,N,K,2]
    const float* sigmas = (const float*)d_in[2]; // [K]
    const float* gw     = (const float*)d_in[3]; // [B,N,K]
    const float* W      = (const float*)d_in[4]; // [K,H,O]
    float* out          = (float*)d_out;

    const int P = in_sizes[3] / KK;              // B*N = 262144

    hermite_prep_kernel<<<(V_DW + 255) / 256, 256, 0, stream>>>(W, sigmas);
    hermite_fused_kernel<<<P / PTS_BLK, 256, 0, stream>>>(mlp, cd, gw, out);
}